// Round 1
// baseline (1417.166 us; speedup 1.0000x reference)
//
#include <hip/hip_runtime.h>
#include <hip/hip_bf16.h>

// Problem constants
#define BATCH 2
#define CIN 512
#define COUT 512
#define RES 256
#define WDIM 512
#define GRIDP 8
#define PW 32          // patch width = RES/GRIDP
#define NPATCH 16      // BATCH*GRIDP
#define LRELU 0.2f
#define ACT_GAIN 1.41421356237309515f

typedef __attribute__((ext_vector_type(8))) short bf16x8;   // 8 bf16 in 4 VGPRs
typedef __attribute__((ext_vector_type(4))) float f32x4;

// Workspace layout (bytes)
#define SZ_XMOD (134217728ULL)                 // [16][256][32][512] bf16
#define OFF_WBF (SZ_XMOD)                      // [9][512][512] bf16
#define SZ_WBF  (9ULL*512*512*2)
#define OFF_STYLES (OFF_WBF + SZ_WBF)          // [2][3][512] f32
#define SZ_STYLES (2*3*512*4)
#define OFF_INVSTD (OFF_STYLES + SZ_STYLES)    // [2][512][8] f32
#define SZ_INVSTD (2*512*8*4)
#define OFF_DEMOD (OFF_INVSTD + SZ_INVSTD)     // [512] f32

// ---------------- Kernel 1: styles = wg @ affine_w^T / sqrt(512) + affine_b ----
__global__ void k_styles(const float* __restrict__ w, const float* __restrict__ wctx,
                         const float* __restrict__ affw, const float* __restrict__ affb,
                         float* __restrict__ styles) {
    int tid = blockIdx.x * 256 + threadIdx.x;
    if (tid >= BATCH * 3 * CIN) return;
    int c = tid & 511;
    int s = (tid >> 9) % 3;
    int b = tid / (3 * 512);
    const float* row = (s == 0) ? (wctx + b * 2 * WDIM)
                     : (s == 1) ? (w + b * WDIM)
                                : (wctx + b * 2 * WDIM + WDIM);
    const float* aw = affw + (size_t)c * WDIM;
    float acc = 0.f;
    for (int d = 0; d < WDIM; ++d) acc += row[d] * aw[d];
    styles[tid] = acc * 0.044194173824159216f + affb[c];
}

// ---------------- Kernel 2: weight -> bf16 [tap][cout][cin], demod[cout] -------
__global__ void k_wprep(const float* __restrict__ weight, __hip_bfloat16* __restrict__ wbf,
                        float* __restrict__ demod) {
    int o = blockIdx.x;          // cout
    int t = threadIdx.x;
    const float* wrow = weight + (size_t)o * 4608;
    float ss = 0.f;
    for (int i = t; i < 4608; i += 256) { float v = wrow[i]; ss += v * v; }
    #pragma unroll
    for (int off = 32; off; off >>= 1) ss += __shfl_down(ss, off, 64);
    __shared__ float red[4];
    if ((t & 63) == 0) red[t >> 6] = ss;
    __syncthreads();
    if (t == 0) {
        float tot = red[0] + red[1] + red[2] + red[3];
        demod[o] = 1.0f / sqrtf(tot + 1e-8f);
    }
    // rearrange: wbf[k][o][ci] = bf16(weight[o][ci][kh][kw]), k = kh*3+kw
    for (int k = 0; k < 9; ++k)
        for (int ci = t; ci < 512; ci += 256)
            wbf[(size_t)k * COUT * CIN + (size_t)o * CIN + ci] = __float2bfloat16(wrow[ci * 9 + k]);
}

// ---------------- Kernel 3: per-(b,c,patch) inv_std (ddof=1) -------------------
__global__ void k_std(const float* __restrict__ x, float* __restrict__ inv_std) {
    int bid = blockIdx.x;                 // [b][c][g]
    int g = bid & 7;
    int c = (bid >> 3) & 511;
    int b = bid >> 12;
    const float* base = x + ((size_t)(b * 512 + c) * 256) * 256 + g * 32;
    int t = threadIdx.x;
    float s = 0.f, ss = 0.f;
    #pragma unroll 4
    for (int i = 0; i < 32; ++i) {
        int e = t + (i << 8);
        int h = e >> 5, wp = e & 31;
        float v = base[h * 256 + wp];
        s += v; ss += v * v;
    }
    #pragma unroll
    for (int off = 32; off; off >>= 1) {
        s += __shfl_down(s, off, 64);
        ss += __shfl_down(ss, off, 64);
    }
    __shared__ float rs[4], rss[4];
    if ((t & 63) == 0) { rs[t >> 6] = s; rss[t >> 6] = ss; }
    __syncthreads();
    if (t == 0) {
        float S = rs[0] + rs[1] + rs[2] + rs[3];
        float SS = rss[0] + rss[1] + rss[2] + rss[3];
        float var = (SS - S * S * (1.f / 8192.f)) * (1.f / 8191.f);
        var = fmaxf(var, 0.f);
        inv_std[bid] = 1.f / (sqrtf(var) + 1e-8f);
    }
}

// ---------------- Kernel 4: normalize * style-lerp -> bf16, transpose ----------
// out layout: xmod[p][h][wp][cin]  (cin contiguous for conv staging)
__global__ void k_normmod(const float* __restrict__ x, const float* __restrict__ styles,
                          const float* __restrict__ inv_std, const int* __restrict__ lbi,
                          __hip_bfloat16* __restrict__ xmod) {
    int bid = blockIdx.x;
    int ht = bid & 31;           // h-tile of 8 rows
    int cc = (bid >> 5) & 7;     // cin chunk of 64
    int p = bid >> 8;            // patch
    int b = p >> 3, g = p & 7;
    int t = threadIdx.x;
    __shared__ float st[3][64];
    __shared__ float istd[64];
    __shared__ __align__(16) __hip_bfloat16 tile[8 * 33 * 66];
    if (t < 192) {
        int s = t / 64, c = t % 64;
        st[s][c] = styles[(b * 3 + s) * 512 + cc * 64 + c];
    } else {
        int c = t - 192;
        istd[c] = inv_std[(b * 512 + cc * 64 + c) * 8 + g];
    }
    __syncthreads();
    float center = (float)(lbi[b] * PW);
    const float* xb = x + ((size_t)(b * 512 + cc * 64) * 256 + ht * 8) * 256 + g * 32;
    #pragma unroll 4
    for (int i = 0; i < 16; ++i) {
        int cell = t + (i << 8);         // over [c:64][h:8][v4:8]
        int c = cell >> 6;
        int rem = cell & 63;
        int h = rem >> 3;
        int v4 = rem & 7;
        float4 xv = *(const float4*)(xb + ((size_t)c * 256 + h) * 256 + v4 * 4);
        float sc = istd[c];
        float s0 = st[0][c], s1 = st[1][c], s2 = st[2][c];
        float colb = (float)(g * 32 + v4 * 4) + 0.5f;
        const float* xvp = &xv.x;
        #pragma unroll
        for (int k = 0; k < 4; ++k) {
            float tc = (colb + (float)k - center) * 0.00390625f;  // /256
            tc = fminf(fmaxf(tc, -1.f), 1.f);
            float a = fmaxf(-tc, 0.f), r = fmaxf(tc, 0.f);
            float m = 1.f - a - r;
            float scol = a * s0 + m * s1 + r * s2;
            tile[(h * 33 + (v4 * 4 + k)) * 66 + c] = __float2bfloat16(xvp[k] * sc * scol);
        }
    }
    __syncthreads();
    __hip_bfloat16* ob = xmod + (size_t)(p * 256 + ht * 8) * 32 * 512 + cc * 64;
    #pragma unroll 4
    for (int i = 0; i < 8; ++i) {
        int cell = t + (i << 8);         // over [h:8][wp:32][c8:8]
        int c8 = cell & 7;
        int wp = (cell >> 3) & 31;
        int h = cell >> 8;
        const __hip_bfloat16* src = tile + (h * 33 + wp) * 66 + c8 * 8;
        uint4 v;
        v.x = *(const unsigned*)(src);
        v.y = *(const unsigned*)(src + 2);
        v.z = *(const unsigned*)(src + 4);
        v.w = *(const unsigned*)(src + 6);
        *(uint4*)(ob + (size_t)(h * 32 + wp) * 512 + c8 * 8) = v;
    }
}

// ---------------- Kernel 5: patchwise 3x3 conv via MFMA + fused epilogue -------
// grid: (64 h-tiles, 16 patches, 4 cout-blocks), block 256 = 4 waves (2x2)
// block tile: 128 cout x 128 spatial (4 h x 32 wp); wave tile 64x64
__global__ void __launch_bounds__(256, 2)
k_conv(const __hip_bfloat16* __restrict__ xmod, const __hip_bfloat16* __restrict__ wbf,
       const float* __restrict__ demod, const float* __restrict__ bias,
       const float* __restrict__ noise, const float* __restrict__ nstr_p,
       float* __restrict__ out) {
    int ht = blockIdx.x;     // 0..63
    int p = blockIdx.y;      // 0..15
    int mb = blockIdx.z;     // 0..3
    int b = p >> 3, g = p & 7;
    int cout0 = mb * 128;
    int h0b = ht * 4;
    int t = threadIdx.x;
    int lane = t & 63, wid = t >> 6;
    int wm = wid >> 1, wn = wid & 1;
    int l15 = lane & 15, q = lane >> 4;

    // wsA[kw][r:128][cin:32] ; xsB cells [k8:4][hs:6][wps:34][8cin] (16B cells)
    __shared__ __align__(16) __hip_bfloat16 wsA[3 * 128 * 32];   // 24576 B
    __shared__ __align__(16) __hip_bfloat16 xsB[4 * 6 * 34 * 8]; // 13056 B

    f32x4 acc[4][4];
    #pragma unroll
    for (int i = 0; i < 4; ++i)
        #pragma unroll
        for (int j = 0; j < 4; ++j) acc[i][j] = (f32x4){0.f, 0.f, 0.f, 0.f};

    const __hip_bfloat16* xpat = xmod + (size_t)p * 256 * 32 * 512;

    for (int cin0 = 0; cin0 < 512; cin0 += 32) {
        __syncthreads();   // protect xsB/wsA from previous iteration's readers
        // ---- stage x slab: 816 cells of 16B; zero cols 0/33 and h out of range
        for (int idx = t; idx < 816; idx += 256) {
            int k8 = idx / 204;
            int rem = idx - k8 * 204;
            int hs = rem / 34;
            int wps = rem - hs * 34;
            int hg = h0b + hs - 1;
            uint4 v = make_uint4(0u, 0u, 0u, 0u);
            if (wps >= 1 && wps <= 32 && hg >= 0 && hg < 256)
                v = *(const uint4*)(xpat + (size_t)(hg * 32 + (wps - 1)) * 512 + cin0 + k8 * 8);
            *(uint4*)(xsB + ((k8 * 6 + hs) * 34 + wps) * 8) = v;
        }
        for (int kh = 0; kh < 3; ++kh) {
            __syncthreads();
            // ---- stage weights for (kh, cin0): [3 kw][128 cout][32 cin]
            for (int idx = t; idx < 1536; idx += 256) {
                int kw = idx >> 9;
                int r = (idx >> 2) & 127;
                int k8 = idx & 3;
                uint4 v = *(const uint4*)(wbf + (size_t)((kh * 3 + kw) * 512 + cout0 + r) * 512 + cin0 + k8 * 8);
                *(uint4*)(wsA + ((kw * 128 + r) * 32 + k8 * 8)) = v;
            }
            __syncthreads();
            #pragma unroll
            for (int kw = 0; kw < 3; ++kw) {
                bf16x8 af[4], bfr[4];
                #pragma unroll
                for (int mf = 0; mf < 4; ++mf)
                    af[mf] = *(const bf16x8*)(wsA + ((kw * 128 + wm * 64 + mf * 16 + l15) * 32 + q * 8));
                #pragma unroll
                for (int j = 0; j < 4; ++j) {
                    int hl = wn * 2 + (j >> 1);
                    int wp0 = (j & 1) * 16;
                    bfr[j] = *(const bf16x8*)(xsB + ((q * 6 + hl + kh) * 34 + wp0 + kw + l15) * 8);
                }
                #pragma unroll
                for (int mf = 0; mf < 4; ++mf)
                    #pragma unroll
                    for (int j = 0; j < 4; ++j)
                        acc[mf][j] = __builtin_amdgcn_mfma_f32_16x16x32_bf16(af[mf], bfr[j], acc[mf][j], 0, 0, 0);
            }
        }
    }

    // ---- epilogue: demod, noise, bias, lrelu*sqrt(2)
    float nstr = nstr_p[0];
    #pragma unroll
    for (int j = 0; j < 4; ++j) {
        int hl = wn * 2 + (j >> 1);
        int hg = h0b + hl;
        int colg = g * 32 + (j & 1) * 16 + l15;
        float nv = noise[(size_t)b * 65536 + hg * 256 + colg] * nstr;
        #pragma unroll
        for (int mf = 0; mf < 4; ++mf) {
            int cbase = cout0 + wm * 64 + mf * 16 + q * 4;
            #pragma unroll
            for (int r = 0; r < 4; ++r) {
                int c = cbase + r;
                float v = acc[mf][j][r] * demod[c] + nv + bias[c];
                v = (v >= 0.f ? v : v * LRELU) * ACT_GAIN;
                out[((size_t)(b * 512 + c) * 256 + hg) * 256 + colg] = v;
            }
        }
    }
}

// ---------------- host ----------------
extern "C" void kernel_launch(void* const* d_in, const int* in_sizes, int n_in,
                              void* d_out, int out_size, void* d_ws, size_t ws_size,
                              hipStream_t stream) {
    const float* x      = (const float*)d_in[0];
    const float* w      = (const float*)d_in[1];
    const float* wctx   = (const float*)d_in[2];
    const float* weight = (const float*)d_in[3];
    const float* affw   = (const float*)d_in[4];
    const float* affb   = (const float*)d_in[5];
    const float* bias   = (const float*)d_in[6];
    const float* nstr   = (const float*)d_in[7];
    const float* noise  = (const float*)d_in[8];
    const int*   lbi    = (const int*)d_in[9];
    float* out = (float*)d_out;

    char* wsb = (char*)d_ws;
    __hip_bfloat16* xmod = (__hip_bfloat16*)wsb;
    __hip_bfloat16* wbf  = (__hip_bfloat16*)(wsb + OFF_WBF);
    float* styles        = (float*)(wsb + OFF_STYLES);
    float* invstd        = (float*)(wsb + OFF_INVSTD);
    float* demod         = (float*)(wsb + OFF_DEMOD);

    k_styles<<<12, 256, 0, stream>>>(w, wctx, affw, affb, styles);
    k_wprep<<<512, 256, 0, stream>>>(weight, wbf, demod);
    k_std<<<8192, 256, 0, stream>>>(x, invstd);
    k_normmod<<<4096, 256, 0, stream>>>(x, styles, invstd, lbi, xmod);
    k_conv<<<dim3(64, 16, 4), 256, 0, stream>>>(xmod, wbf, demod, bias, noise, nstr, out);
}